// Round 6
// baseline (31.149 us; speedup 1.0000x reference)
//
#include <hip/hip_runtime.h>

#define BB 4
#define SS 4096
#define EE 128

typedef __attribute__((ext_vector_type(8))) short bf16x8;
typedef __attribute__((ext_vector_type(4))) float f32x4;

__device__ __forceinline__ unsigned short f2bf(float f) {
    unsigned u = __float_as_uint(f);
    u = (u + 0x7FFFu + ((u >> 16) & 1u)) >> 16;
    return (unsigned short)u;
}
__device__ __forceinline__ float bf2f(unsigned short h) {
    return __uint_as_float(((unsigned)h) << 16);
}
__device__ __forceinline__ void split8(const float* p, bf16x8& h, bf16x8& l) {
    float4 v0 = *reinterpret_cast<const float4*>(p);
    float4 v1 = *reinterpret_cast<const float4*>(p + 4);
    float f[8] = {v0.x, v0.y, v0.z, v0.w, v1.x, v1.y, v1.z, v1.w};
    #pragma unroll
    for (int i = 0; i < 8; ++i) {
        unsigned short hb = f2bf(f[i]);
        h[i] = (short)hb;
        l[i] = (short)f2bf(f[i] - bf2f(hb));
    }
}

// ---------------------------------------------------------------------------
// K1: blocks [0,256): b=bx>>6, i=bx&63: chunk = x[b, 64+i*63 .. +63, :]
//       xsum_i = column sums; vpart[b][i][c] = xsum_i . Wv[c]   (f32)
//     blocks [256,268): idx=bx-256, b=idx/3, role=idx%3 on x[b,0:64]:
//       role 0/1: Vt[b][v][t] = bf16( x64 @ Wv^T )  (transposed store)
//       role 2:   keyT (masked) in LDS, then Mt[b][t][e] = Wq^T @ keyT
//                 stored as bf16 hi/lo. key never hits global.
// LDS: xs[64][132] + wst[128][68] = 68.6 KB (2 blocks/CU).
// ---------------------------------------------------------------------------
__global__ __launch_bounds__(256, 2)
void prep(const float* __restrict__ x, const float* __restrict__ Wk,
          const float* __restrict__ Wq, const float* __restrict__ Wv,
          unsigned short* __restrict__ Vt,
          unsigned short* __restrict__ Mth, unsigned short* __restrict__ Mtl,
          float* __restrict__ vpart)
{
    __shared__ float xs[64][132];
    __shared__ float wst[128][68];
    const int tid = threadIdx.x;
    const int bx = blockIdx.x;

    if (bx < 256) {
        // ---- xpart chunk sum + Wv projection ----
        float* w = &wst[0][0];           // [0:128)=rg0, [128:256)=rg1, [256:384)=xsum
        const int b = bx >> 6, i = bx & 63;
        const size_t base = ((size_t)b * SS + 64 + (size_t)i * 63) * EE;
        const int col = tid & 127, rg = tid >> 7;
        float s = 0.f;
        for (int r = rg; r < 63; r += 2)
            s += x[base + (size_t)r * EE + col];
        w[rg * 128 + col] = s;
        __syncthreads();
        if (tid < 128) w[256 + tid] = w[tid] + w[128 + tid];
        __syncthreads();
        if (tid < 128) {
            float a = 0.f;
            #pragma unroll 8
            for (int e = 0; e < 128; e += 4) {
                float4 wv = *reinterpret_cast<const float4*>(Wv + (size_t)tid * EE + e);
                a = fmaf(w[256 + e + 0], wv.x, a);
                a = fmaf(w[256 + e + 1], wv.y, a);
                a = fmaf(w[256 + e + 2], wv.z, a);
                a = fmaf(w[256 + e + 3], wv.w, a);
            }
            vpart[((size_t)b * 64 + i) * 128 + tid] = a;
        }
        return;
    }

    const int idx = bx - 256;
    const int b = idx / 3, role = idx % 3;
    const size_t xrow0 = (size_t)b * SS;
    const float* Wbase = (role == 0) ? Wv : (role == 1) ? (Wv + 64 * EE) : Wk;

    #pragma unroll
    for (int i = 0; i < 8; ++i) {               // stage x64 (64x128)
        int f4 = tid + i * 256;
        int row = f4 >> 5, kq = f4 & 31;
        float4 v = *reinterpret_cast<const float4*>(x + (xrow0 + row) * EE + 4 * kq);
        *reinterpret_cast<float4*>(&xs[row][4 * kq]) = v;
    }
    #pragma unroll
    for (int i = 0; i < 8; ++i) {               // stage weight rows transposed
        int f4 = tid + i * 256;
        int c = f4 & 63, kq = f4 >> 6;
        float4 v = *reinterpret_cast<const float4*>(Wbase + (size_t)c * EE + 4 * kq);
        wst[4 * kq + 0][c] = v.x;
        wst[4 * kq + 1][c] = v.y;
        wst[4 * kq + 2][c] = v.z;
        wst[4 * kq + 3][c] = v.w;
    }
    __syncthreads();

    const int ct = tid & 15, rt = tid >> 4;
    const int c0 = 4 * ct, r0 = 4 * rt;
    float acc[4][4] = {};
    #pragma unroll 4
    for (int k0 = 0; k0 < 128; k0 += 4) {
        float4 a[4], bq[4];
        #pragma unroll
        for (int i = 0; i < 4; ++i) a[i] = *reinterpret_cast<const float4*>(&xs[r0 + i][k0]);
        #pragma unroll
        for (int kk = 0; kk < 4; ++kk) bq[kk] = *reinterpret_cast<const float4*>(&wst[k0 + kk][c0]);
        #pragma unroll
        for (int i = 0; i < 4; ++i) {
            const float4 ai = a[i];
            acc[i][0] = fmaf(ai.x, bq[0].x, acc[i][0]);
            acc[i][1] = fmaf(ai.x, bq[0].y, acc[i][1]);
            acc[i][2] = fmaf(ai.x, bq[0].z, acc[i][2]);
            acc[i][3] = fmaf(ai.x, bq[0].w, acc[i][3]);
            acc[i][0] = fmaf(ai.y, bq[1].x, acc[i][0]);
            acc[i][1] = fmaf(ai.y, bq[1].y, acc[i][1]);
            acc[i][2] = fmaf(ai.y, bq[1].z, acc[i][2]);
            acc[i][3] = fmaf(ai.y, bq[1].w, acc[i][3]);
            acc[i][0] = fmaf(ai.z, bq[2].x, acc[i][0]);
            acc[i][1] = fmaf(ai.z, bq[2].y, acc[i][1]);
            acc[i][2] = fmaf(ai.z, bq[2].z, acc[i][2]);
            acc[i][3] = fmaf(ai.z, bq[2].w, acc[i][3]);
            acc[i][0] = fmaf(ai.w, bq[3].x, acc[i][0]);
            acc[i][1] = fmaf(ai.w, bq[3].y, acc[i][1]);
            acc[i][2] = fmaf(ai.w, bq[3].z, acc[i][2]);
            acc[i][3] = fmaf(ai.w, bq[3].w, acc[i][3]);
        }
    }

    if (role <= 1) {
        // ---- Vt bf16 transposed store ----
        const int voff = role * 64;
        #pragma unroll
        for (int j = 0; j < 4; ++j) {
            ushort4 pk = make_ushort4(f2bf(acc[0][j]), f2bf(acc[1][j]),
                                      f2bf(acc[2][j]), f2bf(acc[3][j]));
            *reinterpret_cast<ushort4*>(Vt + (size_t)b * 8192 + (size_t)(voff + c0 + j) * 64 + r0) = pk;
        }
        return;
    }

    // ---- role 2: masked keyT -> LDS (overlay wst), Wq -> LDS (overlay xs) ----
    __syncthreads();                             // all GEMM1 reads done
    float (*ks)[68] = reinterpret_cast<float (*)[68]>(&wst[0][0]);   // [k][t]
    #pragma unroll
    for (int i = 0; i < 4; ++i)
        #pragma unroll
        for (int j = 0; j < 4; ++j) {
            const int t = r0 + i, k = c0 + j;
            ks[k][t] = (t <= k) ? acc[i][j] : 0.f;
        }
    #pragma unroll
    for (int i = 0; i < 8; ++i) {               // stage Wq raw [j][e]
        int f4 = tid + i * 256;
        int row = f4 >> 5, kq = f4 & 31;
        float4 v = *reinterpret_cast<const float4*>(Wq + (size_t)row * EE + 4 * kq);
        *reinterpret_cast<float4*>(&xs[row][4 * kq]) = v;
    }
    __syncthreads();

    // ---- GEMM2: Mt[t][e] = sum_j Wq[j][e] * ks[j][t] ----
    const int tt = tid >> 5, te = tid & 31;
    const int t0 = tt * 8, e0 = te * 4;
    float a2[8][4] = {};
    #pragma unroll 8
    for (int j = 0; j < 64; ++j) {
        float4 wq = *reinterpret_cast<const float4*>(&xs[j][e0]);
        float4 ka = *reinterpret_cast<const float4*>(&ks[j][t0]);
        float4 kb = *reinterpret_cast<const float4*>(&ks[j][t0 + 4]);
        float kv[8] = {ka.x, ka.y, ka.z, ka.w, kb.x, kb.y, kb.z, kb.w};
        #pragma unroll
        for (int i = 0; i < 8; ++i) {
            a2[i][0] = fmaf(kv[i], wq.x, a2[i][0]);
            a2[i][1] = fmaf(kv[i], wq.y, a2[i][1]);
            a2[i][2] = fmaf(kv[i], wq.z, a2[i][2]);
            a2[i][3] = fmaf(kv[i], wq.w, a2[i][3]);
        }
    }
    #pragma unroll
    for (int i = 0; i < 8; ++i) {
        unsigned short h0 = f2bf(a2[i][0]), h1 = f2bf(a2[i][1]);
        unsigned short h2 = f2bf(a2[i][2]), h3 = f2bf(a2[i][3]);
        ushort4 hv = make_ushort4(h0, h1, h2, h3);
        ushort4 lv = make_ushort4(f2bf(a2[i][0] - bf2f(h0)),
                                  f2bf(a2[i][1] - bf2f(h1)),
                                  f2bf(a2[i][2] - bf2f(h2)),
                                  f2bf(a2[i][3] - bf2f(h3)));
        const size_t off = (size_t)b * 8192 + (size_t)(t0 + i) * 128 + e0;
        *reinterpret_cast<ushort4*>(Mth + off) = hv;
        *reinterpret_cast<ushort4*>(Mtl + off) = lv;
    }
}

// ---------------------------------------------------------------------------
// main: 1 wave per block, 16 q-rows. vsum prologue (64 fixed-order vpart
// partials, latency hidden under everything), S = x@M via split-bf16 MFMA,
// in-register softmax (+4032 zero-col term), P relayout via LDS,
// out = (P@V + e*vsum) * iz.
// ---------------------------------------------------------------------------
__global__ __launch_bounds__(64)
void attn_main(const float* __restrict__ x, const short* __restrict__ Mth,
               const short* __restrict__ Mtl, const short* __restrict__ Vt,
               const float* __restrict__ vpart, float* __restrict__ out)
{
    __shared__ float Plds[16][68];
    __shared__ float vsS[128];
    const int l = threadIdx.x;
    const int b = blockIdx.y;
    const int s0 = blockIdx.x * 16;
    const int lm = l & 15, lg = l >> 4;

    // ---- vsum reduction: lane owns cols (2l, 2l+1); needed only at the end ----
    float2 vac = make_float2(0.f, 0.f);
    {
        const float* vp = vpart + (size_t)b * 8192 + 2 * l;
        #pragma unroll 8
        for (int i = 0; i < 64; ++i) {
            float2 t = *reinterpret_cast<const float2*>(vp + (size_t)i * 128);
            vac.x += t.x; vac.y += t.y;
        }
    }
    *reinterpret_cast<float2*>(&vsS[2 * l]) = vac;

    // ---- x A-frags (hi/lo split) ----
    bf16x8 xh[4], xl[4];
    const float* xrow = x + ((size_t)b * SS + s0 + lm) * EE + lg * 8;
    #pragma unroll
    for (int kt = 0; kt < 4; ++kt)
        split8(xrow + kt * 32, xh[kt], xl[kt]);

    // ---- S = x @ M : 4 col-tiles x (4 k-tiles x 3 split-mfma) ----
    f32x4 sa[4];
    const short* mh_base = Mth + (size_t)b * 8192 + lg * 8;
    const short* ml_base = Mtl + (size_t)b * 8192 + lg * 8;
    #pragma unroll
    for (int ct = 0; ct < 4; ++ct) {
        f32x4 a = {0.f, 0.f, 0.f, 0.f};
        const size_t trow = (size_t)(ct * 16 + lm) * 128;
        #pragma unroll
        for (int kt = 0; kt < 4; ++kt) {
            bf16x8 mh = *reinterpret_cast<const bf16x8*>(mh_base + trow + kt * 32);
            bf16x8 ml = *reinterpret_cast<const bf16x8*>(ml_base + trow + kt * 32);
            a = __builtin_amdgcn_mfma_f32_16x16x32_bf16(xh[kt], mh, a, 0, 0, 0);
            a = __builtin_amdgcn_mfma_f32_16x16x32_bf16(xl[kt], mh, a, 0, 0, 0);
            a = __builtin_amdgcn_mfma_f32_16x16x32_bf16(xh[kt], ml, a, 0, 0, 0);
        }
        sa[ct] = a;
    }

    // ---- softmax over 4096 cols (64 real + 4032 exact zeros) ----
    float e[4], iz[4];
    #pragma unroll
    for (int r = 0; r < 4; ++r) {
        float m = fmaxf(fmaxf(sa[0][r], sa[1][r]), fmaxf(sa[2][r], sa[3][r]));
        #pragma unroll
        for (int o = 1; o < 16; o <<= 1) m = fmaxf(m, __shfl_xor(m, o));
        m = fmaxf(m, 0.f);
        float w0 = __expf(sa[0][r] - m), w1 = __expf(sa[1][r] - m);
        float w2 = __expf(sa[2][r] - m), w3 = __expf(sa[3][r] - m);
        sa[0][r] = w0; sa[1][r] = w1; sa[2][r] = w2; sa[3][r] = w3;
        float z = (w0 + w1) + (w2 + w3);
        #pragma unroll
        for (int o = 1; o < 16; o <<= 1) z += __shfl_xor(z, o);
        e[r] = __expf(-m);
        z += 4032.f * e[r];
        iz[r] = 1.f / z;
    }

    // ---- P relayout: C/D layout -> A-frag layout via LDS ----
    #pragma unroll
    for (int ct = 0; ct < 4; ++ct)
        #pragma unroll
        for (int r = 0; r < 4; ++r)
            Plds[lg * 4 + r][ct * 16 + lm] = sa[ct][r];
    bf16x8 pf[2];
    #pragma unroll
    for (int kt2 = 0; kt2 < 2; ++kt2) {
        const float* pr = &Plds[lm][kt2 * 32 + lg * 8];
        #pragma unroll
        for (int i = 0; i < 8; ++i) pf[kt2][i] = (short)f2bf(pr[i]);
    }

    // ---- PV + vsum term + normalize + store ----
    const short* vb = Vt + (size_t)b * 8192 + lg * 8;
    const size_t obase = ((size_t)b * SS + s0) * EE;
    #pragma unroll
    for (int ct = 0; ct < 8; ++ct) {
        const int col = ct * 16 + lm;
        bf16x8 v0 = *reinterpret_cast<const bf16x8*>(vb + (size_t)col * 64);
        bf16x8 v1 = *reinterpret_cast<const bf16x8*>(vb + (size_t)col * 64 + 32);
        f32x4 a = {0.f, 0.f, 0.f, 0.f};
        a = __builtin_amdgcn_mfma_f32_16x16x32_bf16(pf[0], v0, a, 0, 0, 0);
        a = __builtin_amdgcn_mfma_f32_16x16x32_bf16(pf[1], v1, a, 0, 0, 0);
        const float vs = vsS[col];
        #pragma unroll
        for (int r = 0; r < 4; ++r)
            out[obase + (size_t)(lg * 4 + r) * EE + col] = (a[r] + e[r] * vs) * iz[r];
    }
}

// ---------------------------------------------------------------------------
extern "C" void kernel_launch(void* const* d_in, const int* in_sizes, int n_in,
                              void* d_out, int out_size, void* d_ws, size_t ws_size,
                              hipStream_t stream)
{
    const float* x  = (const float*)d_in[0];
    const float* Wk = (const float*)d_in[1];
    const float* Wq = (const float*)d_in[2];
    const float* Wv = (const float*)d_in[3];
    float* out = (float*)d_out;

    float* ws = (float*)d_ws;
    float* vpart = ws;                                     // 4*64*128 f32
    unsigned short* Mth = (unsigned short*)(vpart + 32768);// 4*64*128 bf16
    unsigned short* Mtl = Mth + 32768;                     // 4*64*128 bf16
    unsigned short* Vt  = Mtl + 32768;                     // 4*128*64 bf16

    prep<<<268, 256, 0, stream>>>(x, Wk, Wq, Wv, Vt, Mth, Mtl, vpart);
    attn_main<<<dim3(SS / 16, BB), 64, 0, stream>>>(
        x, (const short*)Mth, (const short*)Mtl, (const short*)Vt, vpart, out);
}